// Round 1
// baseline (1685.977 us; speedup 1.0000x reference)
//
#include <hip/hip_runtime.h>
#include <hip/hip_bf16.h>

#define N_IN 200000
#define N_OUT 200000
#define K_VOL 27
#define M_PAIRS 100000
#define C_IN 64
#define C_OUT 64

// output privatization: each block owns RROWS output rows, accumulates in LDS fp32
#define RROWS 128
#define RSHIFT 7                                  // log2(RROWS)
#define NRANGE ((N_OUT + RROWS - 1) / RROWS)      // 1563
#define NBUCKET (K_VOL * NRANGE)                  // 42201
#define NREC (K_VOL * M_PAIRS)                    // 2,700,000

#define MTILE 64
#define LDS_PAD 72   // A-tile row stride: 144B, breaks bank aliasing, keeps 16B align
#define ACC_PAD 68   // acc row stride: 272B (16B-aligned), breaks bank aliasing on ds_add

typedef __attribute__((ext_vector_type(4))) float floatx4;
typedef __attribute__((ext_vector_type(8))) short shortx8;

static __device__ __forceinline__ ushort f32_to_bf16(float f) {
    union { float f; unsigned int u; } x; x.f = f;
    unsigned int u = x.u;
    u += 0x7FFFu + ((u >> 16) & 1u);   // round-to-nearest-even
    return (ushort)(u >> 16);
}

// fp32 -> bf16, 4 elements per thread
__global__ void cvt_feats_kernel(const float* __restrict__ src, ushort* __restrict__ dst, int n4) {
    int i = blockIdx.x * blockDim.x + threadIdx.x;
    if (i >= n4) return;
    float4 v = ((const float4*)src)[i];
    ushort4 o;
    o.x = f32_to_bf16(v.x); o.y = f32_to_bf16(v.y);
    o.z = f32_to_bf16(v.z); o.w = f32_to_bf16(v.w);
    ((ushort4*)dst)[i] = o;
}

// kernel[k][c][o] fp32 -> wt[k][o][c] bf16 (transposed so MFMA B-frags are contiguous)
__global__ void cvt_wt_kernel(const float* __restrict__ w, ushort* __restrict__ wt) {
    int idx = blockIdx.x * blockDim.x + threadIdx.x;
    if (idx >= K_VOL * C_IN * C_OUT) return;
    int k   = idx >> 12;          // / 4096
    int rem = idx & 4095;
    int c   = rem >> 6;
    int o   = rem & 63;
    wt[(k << 12) + (o << 6) + c] = f32_to_bf16(w[idx]);
}

// Phase A1: histogram contributions into (k, range) buckets
__global__ void count_kernel(const int* __restrict__ omap, unsigned int* __restrict__ counts) {
    int m = blockIdx.x * blockDim.x + threadIdx.x;
    if (m >= M_PAIRS) return;
    int k = blockIdx.y;
    int o = omap[k * M_PAIRS + m];
    atomicAdd(&counts[k * NRANGE + (o >> RSHIFT)], 1u);
}

// Phase A2: exclusive scan of 42201 bucket counts (single block), writes offsets + cursor copy
__global__ void scan_kernel(const unsigned int* __restrict__ counts,
                            unsigned int* __restrict__ offsets,
                            unsigned int* __restrict__ cursor) {
    __shared__ unsigned int part[256];
    const int tid = threadIdx.x;
    const int CH = (NBUCKET + 255) / 256;   // 165 buckets per thread
    const int b0 = tid * CH;
    unsigned int s = 0;
    for (int j = 0; j < CH; ++j) {
        int b = b0 + j;
        if (b < NBUCKET) s += counts[b];
    }
    part[tid] = s;
    __syncthreads();
    for (int d = 1; d < 256; d <<= 1) {     // Hillis-Steele inclusive scan
        unsigned int v = (tid >= d) ? part[tid - d] : 0u;
        __syncthreads();
        part[tid] += v;
        __syncthreads();
    }
    unsigned int run = (tid > 0) ? part[tid - 1] : 0u;
    for (int j = 0; j < CH; ++j) {
        int b = b0 + j;
        if (b < NBUCKET) {
            offsets[b] = run;
            cursor[b]  = run;
            run += counts[b];
        }
    }
    if (tid == 255) offsets[NBUCKET] = run;   // == NREC
}

// Phase A3: scatter packed records (g:18 | olocal:7) into bucket-sorted order.
// atomicExch for the record write: 4B payloads from many XCDs share cache lines; a plain
// per-XCD-L2-cached store risks lost-update on writeback. Atomics resolve coherently.
__global__ void scatter_kernel(const int* __restrict__ imap, const int* __restrict__ omap,
                               unsigned int* __restrict__ cursor, unsigned int* __restrict__ records) {
    int m = blockIdx.x * blockDim.x + threadIdx.x;
    if (m >= M_PAIRS) return;
    int k = blockIdx.y;
    int o = omap[k * M_PAIRS + m];
    unsigned int g = (unsigned int)imap[k * M_PAIRS + m];
    unsigned int b = (unsigned int)(k * NRANGE) + (unsigned int)(o >> RSHIFT);
    unsigned int pos = atomicAdd(&cursor[b], 1u);
    atomicExch(&records[pos], g | ((unsigned int)(o & (RROWS - 1)) << 18));
}

// Phase B: per output-range block. For each k: gather -> 64x64x64 bf16 MFMA -> ds_add_f32
// into private LDS accumulator. Single coalesced fp32 write-out with fused bias.
__launch_bounds__(256, 3)
__global__ void spconv_kernel(const ushort* __restrict__ feats,    // [N_IN][64] bf16
                              const ushort* __restrict__ wt,       // [K][64 o][64 c] bf16
                              const unsigned int* __restrict__ offsets,
                              const unsigned int* __restrict__ records,
                              const float* __restrict__ bias,
                              float* __restrict__ out) {
    __shared__ __align__(16) float  accs[RROWS * ACC_PAD];   // 34,816 B
    __shared__ __align__(16) ushort Asm[MTILE * LDS_PAD];    //  9,216 B
    __shared__ int omap_s[MTILE];

    const int tid = threadIdx.x;
    const int bx  = blockIdx.x;
    const int r0  = bx * RROWS;

    // zero the accumulator tile
    for (int idx = tid; idx < (RROWS * ACC_PAD) / 4; idx += 256)
        ((float4*)accs)[idx] = make_float4(0.f, 0.f, 0.f, 0.f);

    const int wave  = tid >> 6;
    const int lane  = tid & 63;
    const int quad  = lane >> 4;
    const int l16   = lane & 15;
    const int rbase = wave * 16;

    for (int k = 0; k < K_VOL; ++k) {
        const unsigned int beg = offsets[k * NRANGE + bx];
        const unsigned int end = offsets[k * NRANGE + bx + 1];
        if (beg == end) continue;

        // B fragments direct from global (8KB/k, L1-resident across the CU's blocks)
        shortx8 bf0[4], bf1[4];
        #pragma unroll
        for (int ct = 0; ct < 4; ++ct) {
            const ushort* wp = &wt[(k << 12) + (ct * 16 + l16) * 64 + quad * 8];
            bf0[ct] = *(const shortx8*)wp;
            bf1[ct] = *(const shortx8*)(wp + 32);
        }

        for (unsigned int t = beg; t < end; t += MTILE) {
            const unsigned int nrem = end - t;
            const int n = (nrem > (unsigned int)MTILE) ? MTILE : (int)nrem;

            // gather A tile: n pair-rows x 64 ch bf16 (rows >= n zero-filled)
            #pragma unroll
            for (int p = 0; p < 2; ++p) {
                int cid = tid + p * 256;
                int row = cid >> 3;
                int ch  = cid & 7;
                shortx8 v = {0, 0, 0, 0, 0, 0, 0, 0};
                if (row < n) {
                    unsigned int g = records[t + row] & 0x3FFFFu;
                    v = *(const shortx8*)&feats[(g << 6) + ch * 8];
                }
                *(shortx8*)&Asm[row * LDS_PAD + ch * 8] = v;
            }
            if (tid < MTILE)
                omap_s[tid] = (tid < n) ? (int)((records[t + tid] >> 18) & (RROWS - 1)) : -1;
            __syncthreads();

            // A fragments: A[m = l16][c = quad*8 + j (+32)]
            const shortx8 a0 = *(const shortx8*)&Asm[(rbase + l16) * LDS_PAD + quad * 8];
            const shortx8 a1 = *(const shortx8*)&Asm[(rbase + l16) * LDS_PAD + 32 + quad * 8];

            #pragma unroll
            for (int ct = 0; ct < 4; ++ct) {
                floatx4 acc = {0.f, 0.f, 0.f, 0.f};
                acc = __builtin_amdgcn_mfma_f32_16x16x32_bf16(a0, bf0[ct], acc, 0, 0, 0);
                acc = __builtin_amdgcn_mfma_f32_16x16x32_bf16(a1, bf1[ct], acc, 0, 0, 0);
                const int col = ct * 16 + l16;
                #pragma unroll
                for (int r = 0; r < 4; ++r) {
                    int rl = rbase + quad * 4 + r;     // C row = quad*4 + reg
                    int ol = omap_s[rl];
                    if (ol >= 0) atomicAdd(&accs[ol * ACC_PAD + col], acc[r]);  // ds_add_f32
                }
            }
            __syncthreads();   // protect Asm/omap_s reuse and acc visibility
        }
    }

    __syncthreads();
    // write out 128 rows x 64 ch, bias fused, each output line written exactly once
    #pragma unroll
    for (int i = 0; i < 8; ++i) {
        int idx  = tid + i * 256;      // 0..2047 float4 slots
        int row  = idx >> 4;
        int c4   = idx & 15;
        int orow = r0 + row;
        if (orow < N_OUT) {
            float4 v = *(float4*)&accs[row * ACC_PAD + c4 * 4];
            const float4 bb = *(const float4*)&bias[c4 * 4];
            v.x += bb.x; v.y += bb.y; v.z += bb.z; v.w += bb.w;
            *(float4*)&out[(orow << 6) + c4 * 4] = v;
        }
    }
}

extern "C" void kernel_launch(void* const* d_in, const int* in_sizes, int n_in,
                              void* d_out, int out_size, void* d_ws, size_t ws_size,
                              hipStream_t stream) {
    const float* in_feats = (const float*)d_in[0];
    const float* kernelw  = (const float*)d_in[1];
    const float* bias     = (const float*)d_in[2];
    const int*   imap     = (const int*)d_in[3];
    const int*   omap     = (const int*)d_in[4];
    float* out = (float*)d_out;

    char* p = (char*)d_ws;
    ushort* feats_bf = (ushort*)p;  p += (size_t)N_IN * C_IN * 2;           // 25.6 MB
    ushort* wt_bf    = (ushort*)p;  p += (size_t)K_VOL * C_IN * C_OUT * 2;  // 216 KB
    unsigned int* counts  = (unsigned int*)p;  p += (size_t)(NBUCKET + 1) * 4;
    unsigned int* offsets = (unsigned int*)p;  p += (size_t)(NBUCKET + 1) * 4;
    unsigned int* cursor  = (unsigned int*)p;  p += (size_t)(NBUCKET + 1) * 4;
    unsigned int* records = (unsigned int*)p;  p += (size_t)NREC * 4;       // 10.8 MB

    hipMemsetAsync(counts, 0, (size_t)NBUCKET * 4, stream);

    int n4 = N_IN * C_IN / 4;
    cvt_feats_kernel<<<(n4 + 255) / 256, 256, 0, stream>>>(in_feats, feats_bf, n4);
    cvt_wt_kernel<<<(K_VOL * C_IN * C_OUT + 255) / 256, 256, 0, stream>>>(kernelw, wt_bf);

    dim3 gmap((M_PAIRS + 255) / 256, K_VOL);
    count_kernel<<<gmap, 256, 0, stream>>>(omap, counts);
    scan_kernel<<<1, 256, 0, stream>>>(counts, offsets, cursor);
    scatter_kernel<<<gmap, 256, 0, stream>>>(imap, omap, cursor, records);

    spconv_kernel<<<NRANGE, 256, 0, stream>>>(feats_bf, wt_bf, offsets, records, bias, out);
}

// Round 2
// 1370.792 us; speedup vs baseline: 1.2299x; 1.2299x over previous
//
#include <hip/hip_runtime.h>
#include <hip/hip_bf16.h>

#define N_IN 200000
#define N_OUT 200000
#define K_VOL 27
#define M_PAIRS 100000
#define C_IN 64
#define C_OUT 64

// output privatization: each block owns RROWS output rows, accumulates in LDS fp32
#define RROWS 128
#define RSHIFT 7
#define NRANGE ((N_OUT + RROWS - 1) / RROWS)      // 1563
#define NBUCKET (K_VOL * NRANGE)                  // 42201 (key = range*27 + k -> range-contiguous)
#define NREC (K_VOL * M_PAIRS)                    // 2,700,000
#define NRECPAD (NREC + 16 * NBUCKET)             // 3,375,216 (buckets padded to x16)

#define ACC_PAD 68      // acc row stride in floats: 272B, spreads ds_add banks (ol*4 mod 32)
#define MAXT 384        // per-block tile table capacity (expected ~135, max ~165)
#define NWAVES 8
#define NTHREADS 512
#define NSLICE 8
#define MSLICE (M_PAIRS / NSLICE)   // 12500

typedef __attribute__((ext_vector_type(4))) float floatx4;
typedef __attribute__((ext_vector_type(8))) short shortx8;

static __device__ __forceinline__ ushort f32_to_bf16(float f) {
    union { float f; unsigned int u; } x; x.f = f;
    unsigned int u = x.u;
    u += 0x7FFFu + ((u >> 16) & 1u);   // round-to-nearest-even
    return (ushort)(u >> 16);
}

// fp32 -> bf16, 4 elements per thread
__global__ void cvt_feats_kernel(const float* __restrict__ src, ushort* __restrict__ dst, int n4) {
    int i = blockIdx.x * blockDim.x + threadIdx.x;
    if (i >= n4) return;
    float4 v = ((const float4*)src)[i];
    ushort4 o;
    o.x = f32_to_bf16(v.x); o.y = f32_to_bf16(v.y);
    o.z = f32_to_bf16(v.z); o.w = f32_to_bf16(v.w);
    ((ushort4*)dst)[i] = o;
}

// kernel[k][c][o] fp32 -> wt[k][o][c] bf16 (transposed so MFMA B-frags are contiguous)
__global__ void cvt_wt_kernel(const float* __restrict__ w, ushort* __restrict__ wt) {
    int idx = blockIdx.x * blockDim.x + threadIdx.x;
    if (idx >= K_VOL * C_IN * C_OUT) return;
    int k   = idx >> 12;
    int rem = idx & 4095;
    int c   = rem >> 6;
    int o   = rem & 63;
    wt[(k << 12) + (o << 6) + c] = f32_to_bf16(w[idx]);
}

// Phase A1: LDS-privatized histogram (kills 2.7M contended global atomics)
__global__ void count_hist_kernel(const int* __restrict__ omap, unsigned int* __restrict__ counts) {
    __shared__ unsigned int hist[NRANGE];
    const int k   = blockIdx.y;
    const int tid = threadIdx.x;
    for (int b = tid; b < NRANGE; b += 256) hist[b] = 0;
    __syncthreads();
    const int m0 = blockIdx.x * MSLICE;
    for (int j = tid; j < MSLICE; j += 256) {
        int o = omap[k * M_PAIRS + m0 + j];
        atomicAdd(&hist[o >> RSHIFT], 1u);
    }
    __syncthreads();
    for (int b = tid; b < NRANGE; b += 256) {
        unsigned int c = hist[b];
        if (c) atomicAdd(&counts[b * K_VOL + k], c);   // NSLICE-way contention only
    }
}

// Phase A2: exclusive scan with per-bucket pad-to-16; 1024 threads (4x shorter serial chains)
__global__ void scan_kernel(const unsigned int* __restrict__ counts,
                            unsigned int* __restrict__ offsets,
                            unsigned int* __restrict__ cursor) {
    __shared__ unsigned int part[1024];
    const int tid = threadIdx.x;
    const int CH  = (NBUCKET + 1023) / 1024;   // 42
    const int b0  = tid * CH;
    unsigned int s = 0;
    for (int j = 0; j < CH; ++j) {
        int b = b0 + j;
        if (b < NBUCKET) s += (counts[b] + 15u) & ~15u;
    }
    part[tid] = s;
    __syncthreads();
    for (int d = 1; d < 1024; d <<= 1) {
        unsigned int v = (tid >= d) ? part[tid - d] : 0u;
        __syncthreads();
        part[tid] += v;
        __syncthreads();
    }
    unsigned int run = (tid > 0) ? part[tid - 1] : 0u;
    for (int j = 0; j < CH; ++j) {
        int b = b0 + j;
        if (b < NBUCKET) {
            offsets[b] = run;
            cursor[b]  = run;
            run += (counts[b] + 15u) & ~15u;
        }
    }
    if (tid == 1023) offsets[NBUCKET] = run;
}

// Phase A3: two-pass block scatter — LDS hist + one chunk-reservation atomic per (block,bin).
// Record payload written with atomicExch (cross-XCD same-line word writes resolve coherently).
__global__ void scatter_kernel(const int* __restrict__ imap, const int* __restrict__ omap,
                               unsigned int* __restrict__ cursor, unsigned int* __restrict__ records) {
    __shared__ unsigned int hist[NRANGE];
    __shared__ unsigned int base_s[NRANGE];
    const int k   = blockIdx.y;
    const int tid = threadIdx.x;
    for (int b = tid; b < NRANGE; b += 256) hist[b] = 0;
    __syncthreads();
    const int m0 = blockIdx.x * MSLICE;
    for (int j = tid; j < MSLICE; j += 256) {
        int o = omap[k * M_PAIRS + m0 + j];
        atomicAdd(&hist[o >> RSHIFT], 1u);
    }
    __syncthreads();
    for (int b = tid; b < NRANGE; b += 256) {
        unsigned int c = hist[b];
        base_s[b] = c ? atomicAdd(&cursor[b * K_VOL + k], c) : 0u;
    }
    __syncthreads();
    for (int b = tid; b < NRANGE; b += 256) hist[b] = 0;   // reuse as local cursor
    __syncthreads();
    for (int j = tid; j < MSLICE; j += 256) {
        int o = omap[k * M_PAIRS + m0 + j];
        int r = o >> RSHIFT;
        unsigned int loc = atomicAdd(&hist[r], 1u);
        unsigned int g   = (unsigned int)imap[k * M_PAIRS + m0 + j];
        atomicExch(&records[base_s[r] + loc], g | ((unsigned int)(o & (RROWS - 1)) << 18));
    }
}

// Phase B: wave-autonomous tiles. Each wave independently processes 16-record tiles
// (A-frags gathered straight to registers, no LDS staging, no per-tile barriers),
// ds_add_f32 into the block's private 128x64 fp32 accumulator. 2 barriers per block total.
__launch_bounds__(NTHREADS, 4)
__global__ void spconv_kernel(const ushort* __restrict__ feats,    // [N_IN][64] bf16
                              const ushort* __restrict__ wt,       // [K][64 o][64 c] bf16
                              const unsigned int* __restrict__ offsets,
                              const unsigned int* __restrict__ records,
                              const float* __restrict__ bias,
                              float* __restrict__ out) {
    __shared__ __align__(16) float accs[RROWS * ACC_PAD];   // 34,816 B
    __shared__ unsigned int  tile_t_s[MAXT];
    __shared__ unsigned char tile_k_s[MAXT];
    __shared__ int ntiles_s;

    const int tid = threadIdx.x;
    const int bx  = blockIdx.x;

    for (int idx = tid; idx < (RROWS * ACC_PAD) / 4; idx += NTHREADS)
        ((float4*)accs)[idx] = make_float4(0.f, 0.f, 0.f, 0.f);

    const int wave = tid >> 6;
    const int lane = tid & 63;
    const int quad = lane >> 4;
    const int l16  = lane & 15;

    // wave 0 builds the tile table: (k, t) per 16-record tile, k ascending
    if (wave == 0) {
        int k = lane;
        unsigned int beg = 0; int nt = 0;
        if (k < K_VOL) {
            beg = offsets[bx * K_VOL + k];
            nt  = (int)((offsets[bx * K_VOL + k + 1] - beg) >> 4);  // padded -> exact
        }
        int x = nt;
        #pragma unroll
        for (int d = 1; d < 32; d <<= 1) {
            int y = __shfl_up(x, d);
            if (lane >= d) x += y;
        }
        int base = x - nt;
        for (int j = 0; j < nt; ++j) {
            int e = base + j;
            if (e < MAXT) { tile_t_s[e] = beg + (unsigned)(j << 4); tile_k_s[e] = (unsigned char)k; }
        }
        if (lane == 31) ntiles_s = (x < MAXT) ? x : MAXT;
    }
    __syncthreads();

    const int ntiles = ntiles_s;
    // contiguous chunk per wave: balanced +-1 tile, k-coherent (few B reloads)
    const int i0 = (ntiles * wave) / NWAVES;
    const int i1 = (ntiles * (wave + 1)) / NWAVES;

    int kcur = -1;
    shortx8 bf0[4], bf1[4];

    for (int i = i0; i < i1; ++i) {
        const unsigned int t = tile_t_s[i];
        const int k = (int)tile_k_s[i];
        if (k != kcur) {                       // wave-uniform branch
            kcur = k;
            #pragma unroll
            for (int ct = 0; ct < 4; ++ct) {
                const ushort* wp = &wt[(k << 12) + (ct * 16 + l16) * 64 + quad * 8];
                bf0[ct] = *(const shortx8*)wp;
                bf1[ct] = *(const shortx8*)(wp + 32);
            }
        }
        // A fragment: row = record l16, c = quad*8 (+32). Pad records (bit31) read a
        // harmless real row (g=0x8080 < N_IN); their C rows are masked at scatter.
        const unsigned int rec = records[t + l16];
        const int4 rr = *(const int4*)&records[t + (quad << 2)];   // 16B-aligned (t % 16 == 0)
        const unsigned int gofs = (rec & 0x3FFFFu) << 6;
        const shortx8 a0 = *(const shortx8*)&feats[gofs + quad * 8];
        const shortx8 a1 = *(const shortx8*)&feats[gofs + 32 + quad * 8];

        const int oa = ((rr.x >> 18) & 127) * ACC_PAD;
        const int ob = ((rr.y >> 18) & 127) * ACC_PAD;
        const int oc = ((rr.z >> 18) & 127) * ACC_PAD;
        const int od = ((rr.w >> 18) & 127) * ACC_PAD;

        #pragma unroll
        for (int ct = 0; ct < 4; ++ct) {
            floatx4 acc = {0.f, 0.f, 0.f, 0.f};
            acc = __builtin_amdgcn_mfma_f32_16x16x32_bf16(a0, bf0[ct], acc, 0, 0, 0);
            acc = __builtin_amdgcn_mfma_f32_16x16x32_bf16(a1, bf1[ct], acc, 0, 0, 0);
            const int col = ct * 16 + l16;
            if (rr.x >= 0) atomicAdd(&accs[oa + col], acc[0]);   // ds_add_f32
            if (rr.y >= 0) atomicAdd(&accs[ob + col], acc[1]);
            if (rr.z >= 0) atomicAdd(&accs[oc + col], acc[2]);
            if (rr.w >= 0) atomicAdd(&accs[od + col], acc[3]);
        }
    }

    __syncthreads();
    // write out 128 rows x 64 ch, bias fused, each output line written exactly once
    const int r0 = bx * RROWS;
    #pragma unroll
    for (int i2 = 0; i2 < (RROWS * 16) / NTHREADS; ++i2) {
        int idx  = tid + i2 * NTHREADS;      // 0..2047 float4 slots
        int row  = idx >> 4;
        int c4   = idx & 15;
        int orow = r0 + row;
        if (orow < N_OUT) {
            float4 v = *(float4*)&accs[row * ACC_PAD + c4 * 4];
            const float4 bb = *(const float4*)&bias[c4 * 4];
            v.x += bb.x; v.y += bb.y; v.z += bb.z; v.w += bb.w;
            *(float4*)&out[(orow << 6) + c4 * 4] = v;
        }
    }
}

extern "C" void kernel_launch(void* const* d_in, const int* in_sizes, int n_in,
                              void* d_out, int out_size, void* d_ws, size_t ws_size,
                              hipStream_t stream) {
    const float* in_feats = (const float*)d_in[0];
    const float* kernelw  = (const float*)d_in[1];
    const float* bias     = (const float*)d_in[2];
    const int*   imap     = (const int*)d_in[3];
    const int*   omap     = (const int*)d_in[4];
    float* out = (float*)d_out;

    char* p = (char*)d_ws;
    ushort* feats_bf = (ushort*)p;  p += (size_t)N_IN * C_IN * 2;                       // 25.6 MB (64B mult)
    ushort* wt_bf    = (ushort*)p;  p += (size_t)K_VOL * C_IN * C_OUT * 2;              // 216 KB (64B mult)
    unsigned int* counts  = (unsigned int*)p;  p += (((size_t)(NBUCKET + 1) * 4 + 63) & ~(size_t)63);
    unsigned int* offsets = (unsigned int*)p;  p += (((size_t)(NBUCKET + 1) * 4 + 63) & ~(size_t)63);
    unsigned int* cursor  = (unsigned int*)p;  p += (((size_t)(NBUCKET + 1) * 4 + 63) & ~(size_t)63);
    unsigned int* records = (unsigned int*)p;  p += (size_t)NRECPAD * 4;                // 13.5 MB

    hipMemsetAsync(counts, 0, (size_t)NBUCKET * 4, stream);
    hipMemsetAsync(records, 0x80, (size_t)NRECPAD * 4, stream);   // pad sentinel: bit31 set

    int n4 = N_IN * C_IN / 4;
    cvt_feats_kernel<<<(n4 + 255) / 256, 256, 0, stream>>>(in_feats, feats_bf, n4);
    cvt_wt_kernel<<<(K_VOL * C_IN * C_OUT + 255) / 256, 256, 0, stream>>>(kernelw, wt_bf);

    dim3 gmap(NSLICE, K_VOL);
    count_hist_kernel<<<gmap, 256, 0, stream>>>(omap, counts);
    scan_kernel<<<1, 1024, 0, stream>>>(counts, offsets, cursor);
    scatter_kernel<<<gmap, 256, 0, stream>>>(imap, omap, cursor, records);

    spconv_kernel<<<NRANGE, NTHREADS, 0, stream>>>(feats_bf, wt_bf, offsets, records, bias, out);
}